// Round 1
// baseline (438.402 us; speedup 1.0000x reference)
//
#include <hip/hip_runtime.h>

typedef __attribute__((ext_vector_type(8))) short short8;
typedef __attribute__((ext_vector_type(4))) float f32x4;
typedef __attribute__((ext_vector_type(4))) float f4;
typedef __attribute__((ext_vector_type(4))) unsigned short u16x4;

#define KMASK -2.3819763e38f

__device__ __forceinline__ unsigned short f2bf(float f) {
    union { float f; unsigned int u; } v; v.f = f;
    unsigned int r = v.u + 0x7fffu + ((v.u >> 16) & 1u);
    return (unsigned short)(r >> 16);
}
__device__ __forceinline__ float bf2f(unsigned short h) {
    union { unsigned int u; float f; } v; v.u = ((unsigned int)h) << 16;
    return v.f;
}
__device__ __forceinline__ void gload_lds16(const void* g, void* l) {
    __builtin_amdgcn_global_load_lds(
        (const __attribute__((address_space(1))) unsigned int*)g,
        (__attribute__((address_space(3))) unsigned int*)l, 16, 0, 0);
}

// ---------------- conversions ----------------

__global__ void conv_x(const float* __restrict__ x, unsigned short* __restrict__ xb) {
    int i = blockIdx.x * 256 + threadIdx.x;
    f4 v = ((const f4*)x)[i];
    u16x4 o;
    o[0] = f2bf(v[0]); o[1] = f2bf(v[1]); o[2] = f2bf(v[2]); o[3] = f2bf(v[3]);
    ((u16x4*)xb)[i] = o;
}

// wqkvt[f][d], f in [0,4096): 0..2047 q (n=f>>7,h=f&127), 2048..3071 k, 3072..4095 v
__global__ void conv_wqkvt(const float* __restrict__ wq, const float* __restrict__ wkv,
                           unsigned short* __restrict__ wt) {
    __shared__ float tile[64 * 65];
    const int d0 = blockIdx.x * 64, f0 = blockIdx.y * 64;
    const int head = f0 >> 7;       // 0..31
    const int h0 = f0 & 127;        // 0 or 64
    const float* src;
    if (head < 16) src = wq + (size_t)head * 2048 * 128;
    else           src = wkv + (size_t)(head - 16) * 2048 * 128;
    {
        int hh = threadIdx.x & 63, dq = threadIdx.x >> 6;
        #pragma unroll
        for (int r = 0; r < 16; ++r) {
            int dd = r * 4 + dq;
            tile[dd * 65 + hh] = src[(size_t)(d0 + dd) * 128 + h0 + hh];
        }
    }
    __syncthreads();
    {
        int dd = threadIdx.x & 63, fq = threadIdx.x >> 6;
        #pragma unroll
        for (int r = 0; r < 16; ++r) {
            int fl = r * 4 + fq;
            wt[(size_t)(f0 + fl) * 2048 + d0 + dd] = f2bf(tile[dd * 65 + fl]);
        }
    }
}

// wo (2048 nh x 2048 d) -> wo_t[d][nh]
__global__ void conv_wot(const float* __restrict__ wo, unsigned short* __restrict__ wt) {
    __shared__ float tile[64 * 65];
    const int d0 = blockIdx.x * 64, r0 = blockIdx.y * 64;
    int cc = threadIdx.x & 63, rq = threadIdx.x >> 6;
    #pragma unroll
    for (int r = 0; r < 16; ++r) {
        int rr = r * 4 + rq;
        tile[rr * 65 + cc] = wo[(size_t)(r0 + rr) * 2048 + d0 + cc];
    }
    __syncthreads();
    #pragma unroll
    for (int r = 0; r < 16; ++r) {
        int rr = r * 4 + rq;
        wt[(size_t)(d0 + rr) * 2048 + r0 + cc] = f2bf(tile[cc * 65 + rr]);
    }
}

// ---------------- GEMM: C[M][N] = A[M][K] * Bt[N][K]^T  (m97 structure) ----------------

template<int WF32>
__global__ __launch_bounds__(256)
void gemm_bt(const unsigned short* __restrict__ A,
             const unsigned short* __restrict__ Bt,
             void* __restrict__ Cv, int M, int N, int K) {
    __shared__ __align__(16) unsigned short As[128 * 64];
    __shared__ __align__(16) unsigned short Bs[128 * 64];
    const int tid = threadIdx.x;
    const int lane = tid & 63, wave = tid >> 6;
    const int wr = wave >> 1, wc = wave & 1;
    const int l15 = lane & 15, l4 = lane >> 4;
    const int brow = blockIdx.y * 128, bcol = blockIdx.x * 128;
    f32x4 acc[4][4] = {};
    const unsigned short* aSrc = A + (size_t)brow * K;
    const unsigned short* bSrc = Bt + (size_t)bcol * K;
    const int nk = K >> 6;
    for (int kt = 0; kt < nk; ++kt) {
        __syncthreads();
        #pragma unroll
        for (int r = 0; r < 4; ++r) {
            int e = (r * 256 + tid) * 8;
            int row = e >> 6, col = e & 63;
            gload_lds16(aSrc + (size_t)row * K + kt * 64 + col, &As[e]);
            gload_lds16(bSrc + (size_t)row * K + kt * 64 + col, &Bs[e]);
        }
        __syncthreads();
        #pragma unroll
        for (int kk = 0; kk < 2; ++kk) {
            short8 af[4], bfr[4];
            #pragma unroll
            for (int m = 0; m < 4; ++m)
                af[m] = *(const short8*)&As[(wr * 64 + m * 16 + l15) * 64 + kk * 32 + l4 * 8];
            #pragma unroll
            for (int n = 0; n < 4; ++n)
                bfr[n] = *(const short8*)&Bs[(wc * 64 + n * 16 + l15) * 64 + kk * 32 + l4 * 8];
            #pragma unroll
            for (int m = 0; m < 4; ++m)
                #pragma unroll
                for (int n = 0; n < 4; ++n)
                    acc[m][n] = __builtin_amdgcn_mfma_f32_16x16x32_bf16(af[m], bfr[n], acc[m][n], 0, 0, 0);
        }
    }
    #pragma unroll
    for (int m = 0; m < 4; ++m)
        #pragma unroll
        for (int n = 0; n < 4; ++n)
            #pragma unroll
            for (int j = 0; j < 4; ++j) {
                int row = brow + wr * 64 + m * 16 + l4 * 4 + j;
                int col = bcol + wc * 64 + n * 16 + l15;
                if (WF32) ((float*)Cv)[(size_t)row * N + col] = acc[m][n][j];
                else ((unsigned short*)Cv)[(size_t)row * N + col] = f2bf(acc[m][n][j]);
            }
}

// ---------------- RoPE + reshape ----------------
// qkv (B*T, 4096) bf16 -> q_r (B,N,T,H) scaled+roped, k_r (B,KH,T,H) roped, v_t (B,KH,H,T)
__global__ void rope_reshape(const unsigned short* __restrict__ qkv,
                             const int* __restrict__ segpos,
                             unsigned short* __restrict__ q_r,
                             unsigned short* __restrict__ k_r,
                             unsigned short* __restrict__ v_t) {
    const int bt = blockIdx.x;          // b*2048 + t
    const int hd = blockIdx.y;          // 0..31
    const int b = bt >> 11, t = bt & 2047;
    const int h = threadIdx.x;          // 0..127
    if (hd >= 24) {                     // V: pass-through, transposed layout
        int kh = hd - 24;
        unsigned short val = qkv[(size_t)bt * 4096 + 3072 + kh * 128 + h];
        v_t[((size_t)(b * 8 + kh) * 128 + h) * 2048 + t] = val;
        return;
    }
    const unsigned short* in = (hd < 16)
        ? qkv + (size_t)bt * 4096 + hd * 128
        : qkv + (size_t)bt * 4096 + 2048 + (hd - 16) * 128;
    int pos = segpos[bt];
    int i = h & 63;
    float ts = powf(10000.f, (float)i * (1.f / 64.f));
    float ang = (float)pos / ts;
    float s, c;
    sincosf(ang, &s, &c);
    float x1 = bf2f(in[i]);
    float x2 = bf2f(in[i + 64]);
    float o = (h < 64) ? (x1 * c - x2 * s) : (x2 * c + x1 * s);
    if (hd < 16) {
        o *= 0.08838834764831845f;
        q_r[((size_t)((b * 16 + hd) * 2048 + t)) * 128 + h] = f2bf(o);
    } else {
        int kh = hd - 16;
        k_r[((size_t)((b * 8 + kh) * 2048 + t)) * 128 + h] = f2bf(o);
    }
}

// ---------------- flash attention (windowed, soft-cap) ----------------
__global__ __launch_bounds__(256)
void attn_kernel(const unsigned short* __restrict__ q_r,
                 const unsigned short* __restrict__ k_r,
                 const unsigned short* __restrict__ v_t,
                 unsigned short* __restrict__ enc) {
    __shared__ __align__(16) unsigned short Ks[64 * 128];   // [s][h]
    __shared__ __align__(16) unsigned short Vt[128 * 64];   // [h][s]
    __shared__ __align__(16) unsigned short Pl[4][16 * 64]; // per-wave P
    const int tid = threadIdx.x, lane = tid & 63, wave = tid >> 6;
    const int l15 = lane & 15, l4 = lane >> 4;
    const int qb = blockIdx.x, n = blockIdx.y, b = blockIdx.z;
    const int kh = n >> 1;
    short8 qf[4];
    {
        const unsigned short* qp =
            q_r + ((size_t)((b * 16 + n) * 2048 + qb * 64 + wave * 16 + l15)) * 128 + l4 * 8;
        #pragma unroll
        for (int kk = 0; kk < 4; ++kk) qf[kk] = *(const short8*)(qp + kk * 32);
    }
    f32x4 Of[8] = {};
    float mrow[4] = {-1e30f, -1e30f, -1e30f, -1e30f};
    float lrow[4] = {};
    int t_lo = qb * 64 - 1023; if (t_lo < 0) t_lo = 0;
    const unsigned short* kbase = k_r + (size_t)(b * 8 + kh) * 2048 * 128;
    const unsigned short* vbase = v_t + (size_t)(b * 8 + kh) * 128 * 2048;
    for (int st = t_lo >> 6; st <= qb; ++st) {
        __syncthreads();
        #pragma unroll
        for (int r = 0; r < 4; ++r) {
            int e = (r * 256 + tid) * 8;
            gload_lds16(kbase + (size_t)(st * 64 + (e >> 7)) * 128 + (e & 127), &Ks[e]);
            gload_lds16(vbase + (size_t)(e >> 6) * 2048 + st * 64 + (e & 63), &Vt[e]);
        }
        __syncthreads();
        f32x4 sf[4] = {};
        #pragma unroll
        for (int nc = 0; nc < 4; ++nc)
            #pragma unroll
            for (int kk = 0; kk < 4; ++kk) {
                short8 bfr = *(const short8*)&Ks[(nc * 16 + l15) * 128 + kk * 32 + l4 * 8];
                sf[nc] = __builtin_amdgcn_mfma_f32_16x16x32_bf16(qf[kk], bfr, sf[nc], 0, 0, 0);
            }
        float scj[4];
        #pragma unroll
        for (int j = 0; j < 4; ++j) {
            int t = qb * 64 + wave * 16 + l4 * 4 + j;
            float vv[4]; float rm = -3.0e38f;
            #pragma unroll
            for (int nc = 0; nc < 4; ++nc) {
                int s = st * 64 + nc * 16 + l15;
                float capped = 50.f * tanhf(sf[nc][j] * 0.02f);
                float val = (s <= t && s > t - 1024) ? capped : KMASK;
                vv[nc] = val; rm = fmaxf(rm, val);
            }
            rm = fmaxf(rm, __shfl_xor(rm, 1));
            rm = fmaxf(rm, __shfl_xor(rm, 2));
            rm = fmaxf(rm, __shfl_xor(rm, 4));
            rm = fmaxf(rm, __shfl_xor(rm, 8));
            float mnew = fmaxf(mrow[j], rm);
            float sc = __expf(mrow[j] - mnew);
            mrow[j] = mnew;
            float ps = 0.f;
            #pragma unroll
            for (int nc = 0; nc < 4; ++nc) {
                float p = __expf(vv[nc] - mnew);
                ps += p;
                Pl[wave][(l4 * 4 + j) * 64 + nc * 16 + l15] = f2bf(p);
            }
            ps += __shfl_xor(ps, 1); ps += __shfl_xor(ps, 2);
            ps += __shfl_xor(ps, 4); ps += __shfl_xor(ps, 8);
            lrow[j] = lrow[j] * sc + ps;
            scj[j] = sc;
        }
        #pragma unroll
        for (int hc = 0; hc < 8; ++hc)
            #pragma unroll
            for (int j = 0; j < 4; ++j) Of[hc][j] *= scj[j];
        #pragma unroll
        for (int ks = 0; ks < 2; ++ks) {
            short8 af = *(const short8*)&Pl[wave][l15 * 64 + ks * 32 + l4 * 8];
            #pragma unroll
            for (int hc = 0; hc < 8; ++hc) {
                short8 bfr = *(const short8*)&Vt[(hc * 16 + l15) * 64 + ks * 32 + l4 * 8];
                Of[hc] = __builtin_amdgcn_mfma_f32_16x16x32_bf16(af, bfr, Of[hc], 0, 0, 0);
            }
        }
    }
    float inv[4];
    #pragma unroll
    for (int j = 0; j < 4; ++j) inv[j] = 1.f / lrow[j];
    #pragma unroll
    for (int hc = 0; hc < 8; ++hc)
        #pragma unroll
        for (int j = 0; j < 4; ++j) {
            size_t row = (size_t)(b * 2048 + qb * 64 + wave * 16 + l4 * 4 + j);
            enc[row * 2048 + n * 128 + hc * 16 + l15] = f2bf(Of[hc][j] * inv[j]);
        }
}

// ---------------- launch ----------------

extern "C" void kernel_launch(void* const* d_in, const int* in_sizes, int n_in,
                              void* d_out, int out_size, void* d_ws, size_t ws_size,
                              hipStream_t stream) {
    const float* x   = (const float*)d_in[0];
    const int* segp  = (const int*)d_in[1];
    // d_in[2] = attn_mask (causal tril) — computed analytically
    const float* wq  = (const float*)d_in[3];
    const float* wkv = (const float*)d_in[4];
    const float* wo  = (const float*)d_in[5];
    float* out = (float*)d_out;
    char* ws = (char*)d_ws;
    if (ws_size < ((size_t)96 << 20)) return;  // need 96 MiB

    unsigned short* xb    = (unsigned short*)(ws);                       // 16 MiB
    unsigned short* wqkvt = (unsigned short*)(ws + ((size_t)16 << 20));  // 16 MiB
    unsigned short* qkv   = (unsigned short*)(ws + ((size_t)32 << 20));  // 32 MiB
    unsigned short* q_r   = (unsigned short*)(ws + ((size_t)64 << 20));  // 16 MiB
    unsigned short* k_r   = (unsigned short*)(ws + ((size_t)80 << 20));  // 8 MiB
    unsigned short* v_t   = (unsigned short*)(ws + ((size_t)88 << 20));  // 8 MiB
    unsigned short* wo_t  = (unsigned short*)(ws);                       // reuse xb after gemm1
    unsigned short* enc   = (unsigned short*)(ws + ((size_t)32 << 20));  // reuse qkv after rope

    conv_x<<<8192, 256, 0, stream>>>(x, xb);
    conv_wqkvt<<<dim3(32, 64), 256, 0, stream>>>(wq, wkv, wqkvt);
    gemm_bt<0><<<dim3(32, 32), 256, 0, stream>>>(xb, wqkvt, qkv, 4096, 4096, 2048);
    rope_reshape<<<dim3(4096, 32), 128, 0, stream>>>(qkv, segp, q_r, k_r, v_t);
    conv_wot<<<dim3(32, 32), 256, 0, stream>>>(wo, wo_t);
    attn_kernel<<<dim3(32, 16, 2), 256, 0, stream>>>(q_r, k_r, v_t, enc);
    gemm_bt<1><<<dim3(16, 32), 256, 0, stream>>>(enc, wo_t, out, 4096, 2048, 2048);
}

// Round 2
// 312.686 us; speedup vs baseline: 1.4021x; 1.4021x over previous
//
#include <hip/hip_runtime.h>

typedef __attribute__((ext_vector_type(8))) short short8;
typedef __attribute__((ext_vector_type(4))) float f32x4;
typedef __attribute__((ext_vector_type(4))) float f4;
typedef __attribute__((ext_vector_type(4))) unsigned short u16x4;

#define KMASK -2.3819763e38f

__device__ __forceinline__ unsigned short f2bf(float f) {
    union { float f; unsigned int u; } v; v.f = f;
    unsigned int r = v.u + 0x7fffu + ((v.u >> 16) & 1u);
    return (unsigned short)(r >> 16);
}
__device__ __forceinline__ float bf2f(unsigned short h) {
    union { unsigned int u; float f; } v; v.u = ((unsigned int)h) << 16;
    return v.f;
}
__device__ __forceinline__ void gload_lds16(const void* g, void* l) {
    __builtin_amdgcn_global_load_lds(
        (const __attribute__((address_space(1))) unsigned int*)g,
        (__attribute__((address_space(3))) unsigned int*)l, 16, 0, 0);
}

// ---------------- conversions ----------------

__global__ void conv_x(const float* __restrict__ x, unsigned short* __restrict__ xb) {
    int i = blockIdx.x * 256 + threadIdx.x;
    f4 v = ((const f4*)x)[i];
    u16x4 o;
    o[0] = f2bf(v[0]); o[1] = f2bf(v[1]); o[2] = f2bf(v[2]); o[3] = f2bf(v[3]);
    ((u16x4*)xb)[i] = o;
}

// wqkvt[f][d], f in [0,4096): 0..2047 q (n=f>>7,h=f&127), 2048..3071 k, 3072..4095 v
__global__ void conv_wqkvt(const float* __restrict__ wq, const float* __restrict__ wkv,
                           unsigned short* __restrict__ wt) {
    __shared__ float tile[64 * 65];
    const int d0 = blockIdx.x * 64, f0 = blockIdx.y * 64;
    const int head = f0 >> 7;       // 0..31
    const int h0 = f0 & 127;        // 0 or 64
    const float* src;
    if (head < 16) src = wq + (size_t)head * 2048 * 128;
    else           src = wkv + (size_t)(head - 16) * 2048 * 128;
    {
        int hh = threadIdx.x & 63, dq = threadIdx.x >> 6;
        #pragma unroll
        for (int r = 0; r < 16; ++r) {
            int dd = r * 4 + dq;
            tile[dd * 65 + hh] = src[(size_t)(d0 + dd) * 128 + h0 + hh];
        }
    }
    __syncthreads();
    {
        int dd = threadIdx.x & 63, fq = threadIdx.x >> 6;
        #pragma unroll
        for (int r = 0; r < 16; ++r) {
            int fl = r * 4 + fq;
            wt[(size_t)(f0 + fl) * 2048 + d0 + dd] = f2bf(tile[dd * 65 + fl]);
        }
    }
}

// wo (2048 nh x 2048 d) -> wo_t[d][nh]
__global__ void conv_wot(const float* __restrict__ wo, unsigned short* __restrict__ wt) {
    __shared__ float tile[64 * 65];
    const int d0 = blockIdx.x * 64, r0 = blockIdx.y * 64;
    int cc = threadIdx.x & 63, rq = threadIdx.x >> 6;
    #pragma unroll
    for (int r = 0; r < 16; ++r) {
        int rr = r * 4 + rq;
        tile[rr * 65 + cc] = wo[(size_t)(r0 + rr) * 2048 + d0 + cc];
    }
    __syncthreads();
    #pragma unroll
    for (int r = 0; r < 16; ++r) {
        int rr = r * 4 + rq;
        wt[(size_t)(d0 + rr) * 2048 + r0 + cc] = f2bf(tile[cc * 65 + rr]);
    }
}

// ---------------- GEMM: C[M][N] = A[M][K] * Bt[N][K]^T  (m97 structure + XCD swizzle) ----------------

template<int WF32>
__global__ __launch_bounds__(256)
void gemm_bt(const unsigned short* __restrict__ A,
             const unsigned short* __restrict__ Bt,
             void* __restrict__ Cv, int M, int N, int K) {
    __shared__ __align__(16) unsigned short As[128 * 64];
    __shared__ __align__(16) unsigned short Bs[128 * 64];
    const int tid = threadIdx.x;
    const int lane = tid & 63, wave = tid >> 6;
    const int wr = wave >> 1, wc = wave & 1;
    const int l15 = lane & 15, l4 = lane >> 4;
    // XCD-aware swizzle (nwg divisible by 8 in all our launches)
    int nwg = gridDim.x * gridDim.y;
    int wg = blockIdx.y * gridDim.x + blockIdx.x;
    int cpx = nwg >> 3;
    int swz = (wg & 7) * cpx + (wg >> 3);
    int bx = swz % gridDim.x, by = swz / gridDim.x;
    const int brow = by * 128, bcol = bx * 128;
    f32x4 acc[4][4] = {};
    const unsigned short* aSrc = A + (size_t)brow * K;
    const unsigned short* bSrc = Bt + (size_t)bcol * K;
    const int nk = K >> 6;
    for (int kt = 0; kt < nk; ++kt) {
        __syncthreads();
        #pragma unroll
        for (int r = 0; r < 4; ++r) {
            int e = (r * 256 + tid) * 8;
            int row = e >> 6, col = e & 63;
            gload_lds16(aSrc + (size_t)row * K + kt * 64 + col, &As[e]);
            gload_lds16(bSrc + (size_t)row * K + kt * 64 + col, &Bs[e]);
        }
        __syncthreads();
        #pragma unroll
        for (int kk = 0; kk < 2; ++kk) {
            short8 af[4], bfr[4];
            #pragma unroll
            for (int m = 0; m < 4; ++m)
                af[m] = *(const short8*)&As[(wr * 64 + m * 16 + l15) * 64 + kk * 32 + l4 * 8];
            #pragma unroll
            for (int n = 0; n < 4; ++n)
                bfr[n] = *(const short8*)&Bs[(wc * 64 + n * 16 + l15) * 64 + kk * 32 + l4 * 8];
            #pragma unroll
            for (int m = 0; m < 4; ++m)
                #pragma unroll
                for (int n = 0; n < 4; ++n)
                    acc[m][n] = __builtin_amdgcn_mfma_f32_16x16x32_bf16(af[m], bfr[n], acc[m][n], 0, 0, 0);
        }
    }
    #pragma unroll
    for (int m = 0; m < 4; ++m)
        #pragma unroll
        for (int n = 0; n < 4; ++n)
            #pragma unroll
            for (int j = 0; j < 4; ++j) {
                int row = brow + wr * 64 + m * 16 + l4 * 4 + j;
                int col = bcol + wc * 64 + n * 16 + l15;
                if (WF32) ((float*)Cv)[(size_t)row * N + col] = acc[m][n][j];
                else ((unsigned short*)Cv)[(size_t)row * N + col] = f2bf(acc[m][n][j]);
            }
}

// ---------------- RoPE + reshape ----------------
__global__ void rope_reshape(const unsigned short* __restrict__ qkv,
                             const int* __restrict__ segpos,
                             unsigned short* __restrict__ q_r,
                             unsigned short* __restrict__ k_r,
                             unsigned short* __restrict__ v_t) {
    const int bt = blockIdx.x;          // b*2048 + t
    const int hd = blockIdx.y;          // 0..31
    const int b = bt >> 11, t = bt & 2047;
    const int h = threadIdx.x;          // 0..127
    if (hd >= 24) {                     // V: pass-through, transposed layout
        int kh = hd - 24;
        unsigned short val = qkv[(size_t)bt * 4096 + 3072 + kh * 128 + h];
        v_t[((size_t)(b * 8 + kh) * 128 + h) * 2048 + t] = val;
        return;
    }
    const unsigned short* in = (hd < 16)
        ? qkv + (size_t)bt * 4096 + hd * 128
        : qkv + (size_t)bt * 4096 + 2048 + (hd - 16) * 128;
    int pos = segpos[bt];
    int i = h & 63;
    // 1/ts = 10000^(-i/64) = exp(-ln(10000)/64 * i)
    float inv_ts = __expf((float)i * (-9.210340371976184f / 64.f));
    float ang = (float)pos * inv_ts;
    float s, c;
    sincosf(ang, &s, &c);
    float x1 = bf2f(in[i]);
    float x2 = bf2f(in[i + 64]);
    float o = (h < 64) ? (x1 * c - x2 * s) : (x2 * c + x1 * s);
    if (hd < 16) {
        o *= 0.08838834764831845f;
        q_r[((size_t)((b * 16 + hd) * 2048 + t)) * 128 + h] = f2bf(o);
    } else {
        int kh = hd - 16;
        k_r[((size_t)((b * 8 + kh) * 2048 + t)) * 128 + h] = f2bf(o);
    }
}

// ---------------- flash attention (windowed, soft-cap) ----------------
// 8 waves / block: waves 0-3 -> head kh*2, waves 4-7 -> head kh*2+1 (shared K/V LDS).
// K/V double-buffered, XOR-swizzled (staged via pre-swizzled global source).

__device__ __forceinline__ void stage_kv(const unsigned short* kbase, const unsigned short* vbase,
                                         unsigned short* Ksb, unsigned short* Vtb,
                                         int st, int tid) {
    #pragma unroll
    for (int r = 0; r < 2; ++r) {
        int e = (r * 512 + tid) * 8;
        int krow = e >> 7, kcol = e & 127;
        gload_lds16(kbase + (size_t)(st * 64 + krow) * 128 + (kcol ^ ((krow & 7) << 3)), Ksb + e);
        int vrow = e >> 6, vcol = e & 63;
        gload_lds16(vbase + (size_t)vrow * 2048 + st * 64 + (vcol ^ ((vrow & 7) << 3)), Vtb + e);
    }
}

__global__ __launch_bounds__(512, 4)
void attn_kernel(const unsigned short* __restrict__ q_r,
                 const unsigned short* __restrict__ k_r,
                 const unsigned short* __restrict__ v_t,
                 unsigned short* __restrict__ enc) {
    __shared__ __align__(16) unsigned short Ks[2][64 * 128];
    __shared__ __align__(16) unsigned short Vt[2][128 * 64];
    __shared__ __align__(16) unsigned short Pl[8][16 * 64];
    const int tid = threadIdx.x, lane = tid & 63, wave = tid >> 6;
    const int l15 = lane & 15, l4 = lane >> 4;
    const int qb = 31 - blockIdx.x;      // heavy blocks first
    const int kh = blockIdx.y, b = blockIdx.z;
    const int n = kh * 2 + (wave >> 2);  // q-head for this wave
    const int wq = wave & 3;             // wave-in-head: rows wq*16..wq*16+15
    short8 qf[4];
    {
        const unsigned short* qp =
            q_r + ((size_t)((b * 16 + n) * 2048 + qb * 64 + wq * 16 + l15)) * 128 + l4 * 8;
        #pragma unroll
        for (int kk = 0; kk < 4; ++kk) qf[kk] = *(const short8*)(qp + kk * 32);
    }
    f32x4 Of[8] = {};
    float mrow[4] = {-1e30f, -1e30f, -1e30f, -1e30f};
    float lrow[4] = {};
    int t_lo = qb * 64 - 1023; if (t_lo < 0) t_lo = 0;
    const int st0 = t_lo >> 6;
    const unsigned short* kbase = k_r + (size_t)(b * 8 + kh) * 2048 * 128;
    const unsigned short* vbase = v_t + (size_t)(b * 8 + kh) * 128 * 2048;

    stage_kv(kbase, vbase, Ks[0], Vt[0], st0, tid);
    __syncthreads();   // implicit vmcnt(0): buffer 0 ready
    int cur = 0;
    for (int st = st0; st <= qb; ++st) {
        if (st < qb)  // prefetch next tile into the other buffer (overlaps compute)
            stage_kv(kbase, vbase, Ks[cur ^ 1], Vt[cur ^ 1], st + 1, tid);
        // ---- QK^T ----
        f32x4 sf[4] = {};
        #pragma unroll
        for (int nc = 0; nc < 4; ++nc) {
            int row = nc * 16 + l15;
            int sw = (l15 & 7) << 3;
            #pragma unroll
            for (int kk = 0; kk < 4; ++kk) {
                short8 bfr = *(const short8*)&Ks[cur][row * 128 + ((kk * 32 + l4 * 8) ^ sw)];
                sf[nc] = __builtin_amdgcn_mfma_f32_16x16x32_bf16(qf[kk], bfr, sf[nc], 0, 0, 0);
            }
        }
        // ---- softcap + mask + online softmax ----
        float scj[4];
        #pragma unroll
        for (int j = 0; j < 4; ++j) {
            int t = qb * 64 + wq * 16 + l4 * 4 + j;
            float vv[4]; float rm = -3.0e38f;
            #pragma unroll
            for (int nc = 0; nc < 4; ++nc) {
                int s = st * 64 + nc * 16 + l15;
                // 50*tanh(x/50) = 50 - 100/(e^{x/25}+1)  (saturates, NaN-free)
                float ex = __expf(sf[nc][j] * 0.04f);
                float capped = 50.f - 100.f * __builtin_amdgcn_rcpf(ex + 1.f);
                float val = (s <= t && s > t - 1024) ? capped : KMASK;
                vv[nc] = val; rm = fmaxf(rm, val);
            }
            rm = fmaxf(rm, __shfl_xor(rm, 1));
            rm = fmaxf(rm, __shfl_xor(rm, 2));
            rm = fmaxf(rm, __shfl_xor(rm, 4));
            rm = fmaxf(rm, __shfl_xor(rm, 8));
            float mnew = fmaxf(mrow[j], rm);
            float sc = __expf(mrow[j] - mnew);
            mrow[j] = mnew;
            float ps = 0.f;
            int prow = l4 * 4 + j;
            int psw = (prow & 7) << 3;
            #pragma unroll
            for (int nc = 0; nc < 4; ++nc) {
                float p = __expf(vv[nc] - mnew);
                ps += p;
                Pl[wave][prow * 64 + ((nc * 16 + l15) ^ psw)] = f2bf(p);
            }
            ps += __shfl_xor(ps, 1); ps += __shfl_xor(ps, 2);
            ps += __shfl_xor(ps, 4); ps += __shfl_xor(ps, 8);
            lrow[j] = lrow[j] * sc + ps;
            scj[j] = sc;
        }
        #pragma unroll
        for (int hc = 0; hc < 8; ++hc)
            #pragma unroll
            for (int j = 0; j < 4; ++j) Of[hc][j] *= scj[j];
        // ---- PV ----
        {
            int asw = (l15 & 7) << 3;
            #pragma unroll
            for (int ks = 0; ks < 2; ++ks) {
                short8 af = *(const short8*)&Pl[wave][l15 * 64 + ((ks * 32 + l4 * 8) ^ asw)];
                #pragma unroll
                for (int hc = 0; hc < 8; ++hc) {
                    int vrow = hc * 16 + l15;
                    short8 bfr = *(const short8*)&Vt[cur][vrow * 64 + ((ks * 32 + l4 * 8) ^ asw)];
                    Of[hc] = __builtin_amdgcn_mfma_f32_16x16x32_bf16(af, bfr, Of[hc], 0, 0, 0);
                }
            }
        }
        __syncthreads();   // drains vmcnt(0): next buffer ready; all reads of cur done
        cur ^= 1;
    }
    float inv[4];
    #pragma unroll
    for (int j = 0; j < 4; ++j) inv[j] = 1.f / lrow[j];
    #pragma unroll
    for (int hc = 0; hc < 8; ++hc)
        #pragma unroll
        for (int j = 0; j < 4; ++j) {
            size_t row = (size_t)(b * 2048 + qb * 64 + wq * 16 + l4 * 4 + j);
            enc[row * 2048 + n * 128 + hc * 16 + l15] = f2bf(Of[hc][j] * inv[j]);
        }
}

// ---------------- launch ----------------

extern "C" void kernel_launch(void* const* d_in, const int* in_sizes, int n_in,
                              void* d_out, int out_size, void* d_ws, size_t ws_size,
                              hipStream_t stream) {
    const float* x   = (const float*)d_in[0];
    const int* segp  = (const int*)d_in[1];
    // d_in[2] = attn_mask (causal tril) — computed analytically
    const float* wq  = (const float*)d_in[3];
    const float* wkv = (const float*)d_in[4];
    const float* wo  = (const float*)d_in[5];
    float* out = (float*)d_out;
    char* ws = (char*)d_ws;
    if (ws_size < ((size_t)96 << 20)) return;  // need 96 MiB

    unsigned short* xb    = (unsigned short*)(ws);                       // 16 MiB
    unsigned short* wqkvt = (unsigned short*)(ws + ((size_t)16 << 20));  // 16 MiB
    unsigned short* qkv   = (unsigned short*)(ws + ((size_t)32 << 20));  // 32 MiB
    unsigned short* q_r   = (unsigned short*)(ws + ((size_t)64 << 20));  // 16 MiB
    unsigned short* k_r   = (unsigned short*)(ws + ((size_t)80 << 20));  // 8 MiB
    unsigned short* v_t   = (unsigned short*)(ws + ((size_t)88 << 20));  // 8 MiB
    unsigned short* wo_t  = (unsigned short*)(ws);                       // reuse xb after gemm1
    unsigned short* enc   = (unsigned short*)(ws + ((size_t)32 << 20));  // reuse qkv after rope

    conv_x<<<8192, 256, 0, stream>>>(x, xb);
    conv_wqkvt<<<dim3(32, 64), 256, 0, stream>>>(wq, wkv, wqkvt);
    gemm_bt<0><<<dim3(32, 32), 256, 0, stream>>>(xb, wqkvt, qkv, 4096, 4096, 2048);
    rope_reshape<<<dim3(4096, 32), 128, 0, stream>>>(qkv, segp, q_r, k_r, v_t);
    conv_wot<<<dim3(32, 32), 256, 0, stream>>>(wo, wo_t);
    attn_kernel<<<dim3(32, 8, 2), 512, 0, stream>>>(q_r, k_r, v_t, enc);
    gemm_bt<1><<<dim3(16, 32), 256, 0, stream>>>(enc, wo_t, out, 4096, 2048, 2048);
}

// Round 3
// 270.193 us; speedup vs baseline: 1.6226x; 1.1573x over previous
//
#include <hip/hip_runtime.h>

typedef __attribute__((ext_vector_type(8))) short short8;
typedef __attribute__((ext_vector_type(4))) float f32x4;
typedef __attribute__((ext_vector_type(4))) float f4;
typedef __attribute__((ext_vector_type(4))) unsigned short u16x4;

#define KMASK -2.3819763e38f

__device__ __forceinline__ unsigned short f2bf(float f) {
    union { float f; unsigned int u; } v; v.f = f;
    unsigned int r = v.u + 0x7fffu + ((v.u >> 16) & 1u);
    return (unsigned short)(r >> 16);
}
__device__ __forceinline__ float bf2f(unsigned short h) {
    union { unsigned int u; float f; } v; v.u = ((unsigned int)h) << 16;
    return v.f;
}
__device__ __forceinline__ void gload_lds16(const void* g, void* l) {
    __builtin_amdgcn_global_load_lds(
        (const __attribute__((address_space(1))) unsigned int*)g,
        (__attribute__((address_space(3))) unsigned int*)l, 16, 0, 0);
}

// ---------------- conversions ----------------

__global__ void conv_x(const float* __restrict__ x, unsigned short* __restrict__ xb) {
    int i = blockIdx.x * 256 + threadIdx.x;
    f4 v = ((const f4*)x)[i];
    u16x4 o;
    o[0] = f2bf(v[0]); o[1] = f2bf(v[1]); o[2] = f2bf(v[2]); o[3] = f2bf(v[3]);
    ((u16x4*)xb)[i] = o;
}

__global__ void conv_wqkvt(const float* __restrict__ wq, const float* __restrict__ wkv,
                           unsigned short* __restrict__ wt) {
    __shared__ float tile[64 * 65];
    const int d0 = blockIdx.x * 64, f0 = blockIdx.y * 64;
    const int head = f0 >> 7;
    const int h0 = f0 & 127;
    const float* src;
    if (head < 16) src = wq + (size_t)head * 2048 * 128;
    else           src = wkv + (size_t)(head - 16) * 2048 * 128;
    {
        int hh = threadIdx.x & 63, dq = threadIdx.x >> 6;
        #pragma unroll
        for (int r = 0; r < 16; ++r) {
            int dd = r * 4 + dq;
            tile[dd * 65 + hh] = src[(size_t)(d0 + dd) * 128 + h0 + hh];
        }
    }
    __syncthreads();
    {
        int dd = threadIdx.x & 63, fq = threadIdx.x >> 6;
        #pragma unroll
        for (int r = 0; r < 16; ++r) {
            int fl = r * 4 + fq;
            wt[(size_t)(f0 + fl) * 2048 + d0 + dd] = f2bf(tile[dd * 65 + fl]);
        }
    }
}

__global__ void conv_wot(const float* __restrict__ wo, unsigned short* __restrict__ wt) {
    __shared__ float tile[64 * 65];
    const int d0 = blockIdx.x * 64, r0 = blockIdx.y * 64;
    int cc = threadIdx.x & 63, rq = threadIdx.x >> 6;
    #pragma unroll
    for (int r = 0; r < 16; ++r) {
        int rr = r * 4 + rq;
        tile[rr * 65 + cc] = wo[(size_t)(r0 + rr) * 2048 + d0 + cc];
    }
    __syncthreads();
    #pragma unroll
    for (int r = 0; r < 16; ++r) {
        int rr = r * 4 + rq;
        wt[(size_t)(d0 + rr) * 2048 + r0 + cc] = f2bf(tile[cc * 65 + rr]);
    }
}

// ---------------- 8-phase 256x256 GEMM (T2+T3+T4+T5, counted vmcnt) ----------------
// C[M][N] = A[M][K] * Bt[N][K]^T, bf16 in, bf16 out.
// 8 waves = 2(M) x 4(N); per-wave output 128x64; BK=64; LDS 128KB (2 bufs).
// Staging order per thread/tile: P1:[Alo0,B0] P2:[Alo1,B1] P3:[B2,B3] P4:[Ahi0,Ahi1]
// vmcnt(4) at end of P1,P2,P4 => every phase's ds_reads see landed data, 4-6 loads
// always in flight (never drained to 0 in steady state).

__global__ __launch_bounds__(512, 2)
void gemm8p(const unsigned short* __restrict__ A,
            const unsigned short* __restrict__ Bt,
            unsigned short* __restrict__ C, int M, int N, int K) {
    __shared__ __align__(16) unsigned short LDS[65536];  // 128 KiB
    const int tid = threadIdx.x, lane = tid & 63, w = tid >> 6;
    const int wr = w >> 2, wc = w & 3;
    const int l15 = lane & 15, l4 = lane >> 4;
    int nwg = gridDim.x * gridDim.y;
    int wg = blockIdx.y * gridDim.x + blockIdx.x;
    int swz = (wg & 7) * (nwg >> 3) + (wg >> 3);
    int bx = swz % gridDim.x, by = swz / gridDim.x;
    const int brow = by * 256, bcol = bx * 256;
    // staging constants (see header comment)
    const int wg_a = w & 3;            // wave within same-wr A-group (4 waves)
    const int wg_b = wr;               // wave within same-wc B-group (2 waves)
    const int rA = wg_a * 8 + (lane >> 3);       // 0..31
    const int rB = wg_b * 8 + (lane >> 3);       // 0..15
    const int cgS = ((lane & 7) ^ (lane >> 3)) * 8;  // pre-swizzled source granule
    const unsigned short* aP = A + (size_t)(brow + wr * 128 + rA) * K + cgS;
    const unsigned short* bP = Bt + (size_t)(bcol + wc * 64 + rB) * K + cgS;
    const int ldsA0 = wr * 8192 + (wg_a * 64 + lane) * 8;
    const int ldsB0 = wc * 4096 + (wg_b * 64 + lane) * 8;
    // ds_read constants
    const int aRd = (wr * 128 + l15) * 64;
    const int bRd = (wc * 64 + l15) * 64;
    const int c0 = ((0 + l4) ^ (l15 & 7)) * 8;   // kk=0 swizzled granule
    const int c1 = ((4 + l4) ^ (l15 & 7)) * 8;   // kk=1
    f32x4 acc[8][4] = {};
    const int nt = K >> 6;
    // ---- prologue: stage tile 0 into buf 0 (canonical order) ----
    gload_lds16(aP,                  &LDS[ldsA0]);
    gload_lds16(bP,                  &LDS[16384 + ldsB0]);
    gload_lds16(aP + (size_t)32 * K, &LDS[ldsA0 + 2048]);
    gload_lds16(bP + (size_t)16 * K, &LDS[16384 + ldsB0 + 1024]);
    gload_lds16(bP + (size_t)32 * K, &LDS[16384 + ldsB0 + 2048]);
    gload_lds16(bP + (size_t)48 * K, &LDS[16384 + ldsB0 + 3072]);
    gload_lds16(aP + (size_t)64 * K, &LDS[ldsA0 + 4096]);
    gload_lds16(aP + (size_t)96 * K, &LDS[ldsA0 + 6144]);
    asm volatile("s_waitcnt vmcnt(4)" ::: "memory");
    __builtin_amdgcn_s_barrier();
    __builtin_amdgcn_sched_barrier(0);

    short8 af[4][2], bl[2][2], bh[2][2];
    for (int t = 0; t < nt; ++t) {
        const int bufA = (t & 1) << 15, bufB = bufA + 16384;
        const bool pf = (t + 1) < nt;
        const int sA = ((t + 1) & 1) << 15, sB = sA + 16384;
        const unsigned short* ap = aP + (t + 1) * 64;
        const unsigned short* bp = bP + (t + 1) * 64;
        // ============ P1 : m0-3 x n0-1 ============
        #pragma unroll
        for (int m = 0; m < 4; ++m) {
            af[m][0] = *(const short8*)&LDS[bufA + aRd + m * 1024 + c0];
            af[m][1] = *(const short8*)&LDS[bufA + aRd + m * 1024 + c1];
        }
        #pragma unroll
        for (int n = 0; n < 2; ++n) {
            bl[n][0] = *(const short8*)&LDS[bufB + bRd + n * 1024 + c0];
            bl[n][1] = *(const short8*)&LDS[bufB + bRd + n * 1024 + c1];
        }
        if (pf) { gload_lds16(ap, &LDS[sA + ldsA0]);
                  gload_lds16(bp, &LDS[sB + ldsB0]); }
        __builtin_amdgcn_s_barrier();
        __builtin_amdgcn_sched_barrier(0);
        __builtin_amdgcn_s_setprio(1);
        #pragma unroll
        for (int m = 0; m < 4; ++m)
            #pragma unroll
            for (int n = 0; n < 2; ++n) {
                acc[m][n] = __builtin_amdgcn_mfma_f32_16x16x32_bf16(af[m][0], bl[n][0], acc[m][n], 0, 0, 0);
                acc[m][n] = __builtin_amdgcn_mfma_f32_16x16x32_bf16(af[m][1], bl[n][1], acc[m][n], 0, 0, 0);
            }
        __builtin_amdgcn_s_setprio(0);
        asm volatile("s_waitcnt vmcnt(4)" ::: "memory");
        __builtin_amdgcn_s_barrier();
        __builtin_amdgcn_sched_barrier(0);
        // ============ P2 : m0-3 x n2-3 ============
        #pragma unroll
        for (int n = 0; n < 2; ++n) {
            bh[n][0] = *(const short8*)&LDS[bufB + bRd + (n + 2) * 1024 + c0];
            bh[n][1] = *(const short8*)&LDS[bufB + bRd + (n + 2) * 1024 + c1];
        }
        if (pf) { gload_lds16(ap + (size_t)32 * K, &LDS[sA + ldsA0 + 2048]);
                  gload_lds16(bp + (size_t)16 * K, &LDS[sB + ldsB0 + 1024]); }
        __builtin_amdgcn_s_barrier();
        __builtin_amdgcn_sched_barrier(0);
        __builtin_amdgcn_s_setprio(1);
        #pragma unroll
        for (int m = 0; m < 4; ++m)
            #pragma unroll
            for (int n = 0; n < 2; ++n) {
                acc[m][n + 2] = __builtin_amdgcn_mfma_f32_16x16x32_bf16(af[m][0], bh[n][0], acc[m][n + 2], 0, 0, 0);
                acc[m][n + 2] = __builtin_amdgcn_mfma_f32_16x16x32_bf16(af[m][1], bh[n][1], acc[m][n + 2], 0, 0, 0);
            }
        __builtin_amdgcn_s_setprio(0);
        asm volatile("s_waitcnt vmcnt(4)" ::: "memory");
        __builtin_amdgcn_s_barrier();
        __builtin_amdgcn_sched_barrier(0);
        // ============ P3 : m4-7 x n0-1 ============
        #pragma unroll
        for (int m = 0; m < 4; ++m) {
            af[m][0] = *(const short8*)&LDS[bufA + aRd + (m + 4) * 1024 + c0];
            af[m][1] = *(const short8*)&LDS[bufA + aRd + (m + 4) * 1024 + c1];
        }
        if (pf) { gload_lds16(bp + (size_t)32 * K, &LDS[sB + ldsB0 + 2048]);
                  gload_lds16(bp + (size_t)48 * K, &LDS[sB + ldsB0 + 3072]); }
        __builtin_amdgcn_s_barrier();
        __builtin_amdgcn_sched_barrier(0);
        __builtin_amdgcn_s_setprio(1);
        #pragma unroll
        for (int m = 0; m < 4; ++m)
            #pragma unroll
            for (int n = 0; n < 2; ++n) {
                acc[m + 4][n] = __builtin_amdgcn_mfma_f32_16x16x32_bf16(af[m][0], bl[n][0], acc[m + 4][n], 0, 0, 0);
                acc[m + 4][n] = __builtin_amdgcn_mfma_f32_16x16x32_bf16(af[m][1], bl[n][1], acc[m + 4][n], 0, 0, 0);
            }
        __builtin_amdgcn_s_setprio(0);
        __builtin_amdgcn_s_barrier();
        __builtin_amdgcn_sched_barrier(0);
        // ============ P4 : m4-7 x n2-3 ============
        if (pf) { gload_lds16(ap + (size_t)64 * K, &LDS[sA + ldsA0 + 4096]);
                  gload_lds16(ap + (size_t)96 * K, &LDS[sA + ldsA0 + 6144]); }
        __builtin_amdgcn_s_barrier();
        __builtin_amdgcn_sched_barrier(0);
        __builtin_amdgcn_s_setprio(1);
        #pragma unroll
        for (int m = 0; m < 4; ++m)
            #pragma unroll
            for (int n = 0; n < 2; ++n) {
                acc[m + 4][n + 2] = __builtin_amdgcn_mfma_f32_16x16x32_bf16(af[m][0], bh[n][0], acc[m + 4][n + 2], 0, 0, 0);
                acc[m + 4][n + 2] = __builtin_amdgcn_mfma_f32_16x16x32_bf16(af[m][1], bh[n][1], acc[m + 4][n + 2], 0, 0, 0);
            }
        __builtin_amdgcn_s_setprio(0);
        asm volatile("s_waitcnt vmcnt(4)" ::: "memory");
        __builtin_amdgcn_s_barrier();
        __builtin_amdgcn_sched_barrier(0);
    }
    // ---- epilogue: C write (bf16) ----
    #pragma unroll
    for (int m = 0; m < 8; ++m)
        #pragma unroll
        for (int n = 0; n < 4; ++n)
            #pragma unroll
            for (int j = 0; j < 4; ++j) {
                int row = brow + wr * 128 + m * 16 + l4 * 4 + j;
                int col = bcol + wc * 64 + n * 16 + l15;
                C[(size_t)row * N + col] = f2bf(acc[m][n][j]);
            }
}

// ---------------- GEMM: C[M][N] = A[M][K] * Bt[N][K]^T  (m97 structure + XCD swizzle) ----------------

template<int WF32>
__global__ __launch_bounds__(256)
void gemm_bt(const unsigned short* __restrict__ A,
             const unsigned short* __restrict__ Bt,
             void* __restrict__ Cv, int M, int N, int K) {
    __shared__ __align__(16) unsigned short As[128 * 64];
    __shared__ __align__(16) unsigned short Bs[128 * 64];
    const int tid = threadIdx.x;
    const int lane = tid & 63, wave = tid >> 6;
    const int wr = wave >> 1, wc = wave & 1;
    const int l15 = lane & 15, l4 = lane >> 4;
    int nwg = gridDim.x * gridDim.y;
    int wg = blockIdx.y * gridDim.x + blockIdx.x;
    int cpx = nwg >> 3;
    int swz = (wg & 7) * cpx + (wg >> 3);
    int bx = swz % gridDim.x, by = swz / gridDim.x;
    const int brow = by * 128, bcol = bx * 128;
    f32x4 acc[4][4] = {};
    const unsigned short* aSrc = A + (size_t)brow * K;
    const unsigned short* bSrc = Bt + (size_t)bcol * K;
    const int nk = K >> 6;
    for (int kt = 0; kt < nk; ++kt) {
        __syncthreads();
        #pragma unroll
        for (int r = 0; r < 4; ++r) {
            int e = (r * 256 + tid) * 8;
            int row = e >> 6, col = e & 63;
            gload_lds16(aSrc + (size_t)row * K + kt * 64 + col, &As[e]);
            gload_lds16(bSrc + (size_t)row * K + kt * 64 + col, &Bs[e]);
        }
        __syncthreads();
        #pragma unroll
        for (int kk = 0; kk < 2; ++kk) {
            short8 af[4], bfr[4];
            #pragma unroll
            for (int m = 0; m < 4; ++m)
                af[m] = *(const short8*)&As[(wr * 64 + m * 16 + l15) * 64 + kk * 32 + l4 * 8];
            #pragma unroll
            for (int n = 0; n < 4; ++n)
                bfr[n] = *(const short8*)&Bs[(wc * 64 + n * 16 + l15) * 64 + kk * 32 + l4 * 8];
            #pragma unroll
            for (int m = 0; m < 4; ++m)
                #pragma unroll
                for (int n = 0; n < 4; ++n)
                    acc[m][n] = __builtin_amdgcn_mfma_f32_16x16x32_bf16(af[m], bfr[n], acc[m][n], 0, 0, 0);
        }
    }
    #pragma unroll
    for (int m = 0; m < 4; ++m)
        #pragma unroll
        for (int n = 0; n < 4; ++n)
            #pragma unroll
            for (int j = 0; j < 4; ++j) {
                int row = brow + wr * 64 + m * 16 + l4 * 4 + j;
                int col = bcol + wc * 64 + n * 16 + l15;
                if (WF32) ((float*)Cv)[(size_t)row * N + col] = acc[m][n][j];
                else ((unsigned short*)Cv)[(size_t)row * N + col] = f2bf(acc[m][n][j]);
            }
}

// ---------------- RoPE + reshape ----------------
__global__ void rope_reshape(const unsigned short* __restrict__ qkv,
                             const int* __restrict__ segpos,
                             unsigned short* __restrict__ q_r,
                             unsigned short* __restrict__ k_r,
                             unsigned short* __restrict__ v_t) {
    const int bt = blockIdx.x;
    const int hd = blockIdx.y;
    const int b = bt >> 11, t = bt & 2047;
    const int h = threadIdx.x;
    if (hd >= 24) {
        int kh = hd - 24;
        unsigned short val = qkv[(size_t)bt * 4096 + 3072 + kh * 128 + h];
        v_t[((size_t)(b * 8 + kh) * 128 + h) * 2048 + t] = val;
        return;
    }
    const unsigned short* in = (hd < 16)
        ? qkv + (size_t)bt * 4096 + hd * 128
        : qkv + (size_t)bt * 4096 + 2048 + (hd - 16) * 128;
    int pos = segpos[bt];
    int i = h & 63;
    float inv_ts = __expf((float)i * (-9.210340371976184f / 64.f));
    float ang = (float)pos * inv_ts;
    float s, c;
    sincosf(ang, &s, &c);
    float x1 = bf2f(in[i]);
    float x2 = bf2f(in[i + 64]);
    float o = (h < 64) ? (x1 * c - x2 * s) : (x2 * c + x1 * s);
    if (hd < 16) {
        o *= 0.08838834764831845f;
        q_r[((size_t)((b * 16 + hd) * 2048 + t)) * 128 + h] = f2bf(o);
    } else {
        int kh = hd - 16;
        k_r[((size_t)((b * 8 + kh) * 2048 + t)) * 128 + h] = f2bf(o);
    }
}

// ---------------- flash attention (windowed, soft-cap) ----------------

__device__ __forceinline__ void stage_kv(const unsigned short* kbase, const unsigned short* vbase,
                                         unsigned short* Ksb, unsigned short* Vtb,
                                         int st, int tid) {
    #pragma unroll
    for (int r = 0; r < 2; ++r) {
        int e = (r * 512 + tid) * 8;
        int krow = e >> 7, kcol = e & 127;
        gload_lds16(kbase + (size_t)(st * 64 + krow) * 128 + (kcol ^ ((krow & 7) << 3)), Ksb + e);
        int vrow = e >> 6, vcol = e & 63;
        gload_lds16(vbase + (size_t)vrow * 2048 + st * 64 + (vcol ^ ((vrow & 7) << 3)), Vtb + e);
    }
}

__global__ __launch_bounds__(512, 4)
void attn_kernel(const unsigned short* __restrict__ q_r,
                 const unsigned short* __restrict__ k_r,
                 const unsigned short* __restrict__ v_t,
                 unsigned short* __restrict__ enc) {
    __shared__ __align__(16) unsigned short Ks[2][64 * 128];
    __shared__ __align__(16) unsigned short Vt[2][128 * 64];
    __shared__ __align__(16) unsigned short Pl[8][16 * 64];
    const int tid = threadIdx.x, lane = tid & 63, wave = tid >> 6;
    const int l15 = lane & 15, l4 = lane >> 4;
    const int qb = 31 - blockIdx.x;
    const int kh = blockIdx.y, b = blockIdx.z;
    const int n = kh * 2 + (wave >> 2);
    const int wq = wave & 3;
    short8 qf[4];
    {
        const unsigned short* qp =
            q_r + ((size_t)((b * 16 + n) * 2048 + qb * 64 + wq * 16 + l15)) * 128 + l4 * 8;
        #pragma unroll
        for (int kk = 0; kk < 4; ++kk) qf[kk] = *(const short8*)(qp + kk * 32);
    }
    f32x4 Of[8] = {};
    float mrow[4] = {-1e30f, -1e30f, -1e30f, -1e30f};
    float lrow[4] = {};
    int t_lo = qb * 64 - 1023; if (t_lo < 0) t_lo = 0;
    const int st0 = t_lo >> 6;
    const unsigned short* kbase = k_r + (size_t)(b * 8 + kh) * 2048 * 128;
    const unsigned short* vbase = v_t + (size_t)(b * 8 + kh) * 128 * 2048;

    stage_kv(kbase, vbase, Ks[0], Vt[0], st0, tid);
    __syncthreads();
    int cur = 0;
    for (int st = st0; st <= qb; ++st) {
        if (st < qb)
            stage_kv(kbase, vbase, Ks[cur ^ 1], Vt[cur ^ 1], st + 1, tid);
        f32x4 sf[4] = {};
        #pragma unroll
        for (int nc = 0; nc < 4; ++nc) {
            int row = nc * 16 + l15;
            int sw = (l15 & 7) << 3;
            #pragma unroll
            for (int kk = 0; kk < 4; ++kk) {
                short8 bfr = *(const short8*)&Ks[cur][row * 128 + ((kk * 32 + l4 * 8) ^ sw)];
                sf[nc] = __builtin_amdgcn_mfma_f32_16x16x32_bf16(qf[kk], bfr, sf[nc], 0, 0, 0);
            }
        }
        float scj[4];
        #pragma unroll
        for (int j = 0; j < 4; ++j) {
            int t = qb * 64 + wq * 16 + l4 * 4 + j;
            float vv[4]; float rm = -3.0e38f;
            #pragma unroll
            for (int nc = 0; nc < 4; ++nc) {
                int s = st * 64 + nc * 16 + l15;
                float ex = __expf(sf[nc][j] * 0.04f);
                float capped = 50.f - 100.f * __builtin_amdgcn_rcpf(ex + 1.f);
                float val = (s <= t && s > t - 1024) ? capped : KMASK;
                vv[nc] = val; rm = fmaxf(rm, val);
            }
            rm = fmaxf(rm, __shfl_xor(rm, 1));
            rm = fmaxf(rm, __shfl_xor(rm, 2));
            rm = fmaxf(rm, __shfl_xor(rm, 4));
            rm = fmaxf(rm, __shfl_xor(rm, 8));
            float mnew = fmaxf(mrow[j], rm);
            float sc = __expf(mrow[j] - mnew);
            mrow[j] = mnew;
            float ps = 0.f;
            int prow = l4 * 4 + j;
            int psw = (prow & 7) << 3;
            #pragma unroll
            for (int nc = 0; nc < 4; ++nc) {
                float p = __expf(vv[nc] - mnew);
                ps += p;
                Pl[wave][prow * 64 + ((nc * 16 + l15) ^ psw)] = f2bf(p);
            }
            ps += __shfl_xor(ps, 1); ps += __shfl_xor(ps, 2);
            ps += __shfl_xor(ps, 4); ps += __shfl_xor(ps, 8);
            lrow[j] = lrow[j] * sc + ps;
            scj[j] = sc;
        }
        #pragma unroll
        for (int hc = 0; hc < 8; ++hc)
            #pragma unroll
            for (int j = 0; j < 4; ++j) Of[hc][j] *= scj[j];
        {
            int asw = (l15 & 7) << 3;
            #pragma unroll
            for (int ks = 0; ks < 2; ++ks) {
                short8 af = *(const short8*)&Pl[wave][l15 * 64 + ((ks * 32 + l4 * 8) ^ asw)];
                #pragma unroll
                for (int hc = 0; hc < 8; ++hc) {
                    int vrow = hc * 16 + l15;
                    short8 bfr = *(const short8*)&Vt[cur][vrow * 64 + ((ks * 32 + l4 * 8) ^ asw)];
                    Of[hc] = __builtin_amdgcn_mfma_f32_16x16x32_bf16(af, bfr, Of[hc], 0, 0, 0);
                }
            }
        }
        __syncthreads();
        cur ^= 1;
    }
    float inv[4];
    #pragma unroll
    for (int j = 0; j < 4; ++j) inv[j] = 1.f / lrow[j];
    #pragma unroll
    for (int hc = 0; hc < 8; ++hc)
        #pragma unroll
        for (int j = 0; j < 4; ++j) {
            size_t row = (size_t)(b * 2048 + qb * 64 + wq * 16 + l4 * 4 + j);
            enc[row * 2048 + n * 128 + hc * 16 + l15] = f2bf(Of[hc][j] * inv[j]);
        }
}

// ---------------- launch ----------------

extern "C" void kernel_launch(void* const* d_in, const int* in_sizes, int n_in,
                              void* d_out, int out_size, void* d_ws, size_t ws_size,
                              hipStream_t stream) {
    const float* x   = (const float*)d_in[0];
    const int* segp  = (const int*)d_in[1];
    const float* wq  = (const float*)d_in[3];
    const float* wkv = (const float*)d_in[4];
    const float* wo  = (const float*)d_in[5];
    float* out = (float*)d_out;
    char* ws = (char*)d_ws;
    if (ws_size < ((size_t)96 << 20)) return;

    unsigned short* xb    = (unsigned short*)(ws);
    unsigned short* wqkvt = (unsigned short*)(ws + ((size_t)16 << 20));
    unsigned short* qkv   = (unsigned short*)(ws + ((size_t)32 << 20));
    unsigned short* q_r   = (unsigned short*)(ws + ((size_t)64 << 20));
    unsigned short* k_r   = (unsigned short*)(ws + ((size_t)80 << 20));
    unsigned short* v_t   = (unsigned short*)(ws + ((size_t)88 << 20));
    unsigned short* wo_t  = (unsigned short*)(ws);
    unsigned short* enc   = (unsigned short*)(ws + ((size_t)32 << 20));

    conv_x<<<8192, 256, 0, stream>>>(x, xb);
    conv_wqkvt<<<dim3(32, 64), 256, 0, stream>>>(wq, wkv, wqkvt);
    gemm8p<<<dim3(16, 16), 512, 0, stream>>>(xb, wqkvt, qkv, 4096, 4096, 2048);
    rope_reshape<<<dim3(4096, 32), 128, 0, stream>>>(qkv, segp, q_r, k_r, v_t);
    conv_wot<<<dim3(32, 32), 256, 0, stream>>>(wo, wo_t);
    attn_kernel<<<dim3(32, 8, 2), 512, 0, stream>>>(q_r, k_r, v_t, enc);
    gemm_bt<1><<<dim3(16, 32), 256, 0, stream>>>(enc, wo_t, out, 4096, 2048, 2048);
}

// Round 4
// 208.286 us; speedup vs baseline: 2.1048x; 1.2972x over previous
//
#include <hip/hip_runtime.h>

typedef __attribute__((ext_vector_type(8))) short short8;
typedef __attribute__((ext_vector_type(4))) float f32x4;
typedef __attribute__((ext_vector_type(4))) float f4;
typedef __attribute__((ext_vector_type(4))) unsigned short u16x4;

__device__ __forceinline__ unsigned short f2bf(float f) {
    union { float f; unsigned int u; } v; v.f = f;
    unsigned int r = v.u + 0x7fffu + ((v.u >> 16) & 1u);
    return (unsigned short)(r >> 16);
}
__device__ __forceinline__ float bf2f(unsigned short h) {
    union { unsigned int u; float f; } v; v.u = ((unsigned int)h) << 16;
    return v.f;
}
__device__ __forceinline__ void gload_lds16(const void* g, void* l) {
    __builtin_amdgcn_global_load_lds(
        (const __attribute__((address_space(1))) unsigned int*)g,
        (__attribute__((address_space(3))) unsigned int*)l, 16, 0, 0);
}

// ---------------- conversions ----------------

__global__ void conv_x(const float* __restrict__ x, unsigned short* __restrict__ xb) {
    int i = blockIdx.x * 256 + threadIdx.x;
    f4 v = ((const f4*)x)[i];
    u16x4 o;
    o[0] = f2bf(v[0]); o[1] = f2bf(v[1]); o[2] = f2bf(v[2]); o[3] = f2bf(v[3]);
    ((u16x4*)xb)[i] = o;
}

__global__ void conv_wqkvt(const float* __restrict__ wq, const float* __restrict__ wkv,
                           unsigned short* __restrict__ wt) {
    __shared__ float tile[64 * 65];
    const int d0 = blockIdx.x * 64, f0 = blockIdx.y * 64;
    const int head = f0 >> 7;
    const int h0 = f0 & 127;
    const float* src;
    if (head < 16) src = wq + (size_t)head * 2048 * 128;
    else           src = wkv + (size_t)(head - 16) * 2048 * 128;
    {
        int hh = threadIdx.x & 63, dq = threadIdx.x >> 6;
        #pragma unroll
        for (int r = 0; r < 16; ++r) {
            int dd = r * 4 + dq;
            tile[dd * 65 + hh] = src[(size_t)(d0 + dd) * 128 + h0 + hh];
        }
    }
    __syncthreads();
    {
        int dd = threadIdx.x & 63, fq = threadIdx.x >> 6;
        #pragma unroll
        for (int r = 0; r < 16; ++r) {
            int fl = r * 4 + fq;
            wt[(size_t)(f0 + fl) * 2048 + d0 + dd] = f2bf(tile[dd * 65 + fl]);
        }
    }
}

__global__ void conv_wot(const float* __restrict__ wo, unsigned short* __restrict__ wt) {
    __shared__ float tile[64 * 65];
    const int d0 = blockIdx.x * 64, r0 = blockIdx.y * 64;
    int cc = threadIdx.x & 63, rq = threadIdx.x >> 6;
    #pragma unroll
    for (int r = 0; r < 16; ++r) {
        int rr = r * 4 + rq;
        tile[rr * 65 + cc] = wo[(size_t)(r0 + rr) * 2048 + d0 + cc];
    }
    __syncthreads();
    #pragma unroll
    for (int r = 0; r < 16; ++r) {
        int rr = r * 4 + rq;
        wt[(size_t)(d0 + rr) * 2048 + r0 + cc] = f2bf(tile[cc * 65 + rr]);
    }
}

// ---------------- 8-phase 256x256 GEMM (QKV) — unchanged from r3 ----------------

__global__ __launch_bounds__(512, 2)
void gemm8p(const unsigned short* __restrict__ A,
            const unsigned short* __restrict__ Bt,
            unsigned short* __restrict__ C, int M, int N, int K) {
    __shared__ __align__(16) unsigned short LDS[65536];
    const int tid = threadIdx.x, lane = tid & 63, w = tid >> 6;
    const int wr = w >> 2, wc = w & 3;
    const int l15 = lane & 15, l4 = lane >> 4;
    int nwg = gridDim.x * gridDim.y;
    int wg = blockIdx.y * gridDim.x + blockIdx.x;
    int swz = (wg & 7) * (nwg >> 3) + (wg >> 3);
    int bx = swz % gridDim.x, by = swz / gridDim.x;
    const int brow = by * 256, bcol = bx * 256;
    const int wg_a = w & 3;
    const int wg_b = wr;
    const int rA = wg_a * 8 + (lane >> 3);
    const int rB = wg_b * 8 + (lane >> 3);
    const int cgS = ((lane & 7) ^ (lane >> 3)) * 8;
    const unsigned short* aP = A + (size_t)(brow + wr * 128 + rA) * K + cgS;
    const unsigned short* bP = Bt + (size_t)(bcol + wc * 64 + rB) * K + cgS;
    const int ldsA0 = wr * 8192 + (wg_a * 64 + lane) * 8;
    const int ldsB0 = wc * 4096 + (wg_b * 64 + lane) * 8;
    const int aRd = (wr * 128 + l15) * 64;
    const int bRd = (wc * 64 + l15) * 64;
    const int c0 = ((0 + l4) ^ (l15 & 7)) * 8;
    const int c1 = ((4 + l4) ^ (l15 & 7)) * 8;
    f32x4 acc[8][4] = {};
    const int nt = K >> 6;
    gload_lds16(aP,                  &LDS[ldsA0]);
    gload_lds16(bP,                  &LDS[16384 + ldsB0]);
    gload_lds16(aP + (size_t)32 * K, &LDS[ldsA0 + 2048]);
    gload_lds16(bP + (size_t)16 * K, &LDS[16384 + ldsB0 + 1024]);
    gload_lds16(bP + (size_t)32 * K, &LDS[16384 + ldsB0 + 2048]);
    gload_lds16(bP + (size_t)48 * K, &LDS[16384 + ldsB0 + 3072]);
    gload_lds16(aP + (size_t)64 * K, &LDS[ldsA0 + 4096]);
    gload_lds16(aP + (size_t)96 * K, &LDS[ldsA0 + 6144]);
    asm volatile("s_waitcnt vmcnt(4)" ::: "memory");
    __builtin_amdgcn_s_barrier();
    __builtin_amdgcn_sched_barrier(0);

    short8 af[4][2], bl[2][2], bh[2][2];
    for (int t = 0; t < nt; ++t) {
        const int bufA = (t & 1) << 15, bufB = bufA + 16384;
        const bool pf = (t + 1) < nt;
        const int sA = ((t + 1) & 1) << 15, sB = sA + 16384;
        const unsigned short* ap = aP + (t + 1) * 64;
        const unsigned short* bp = bP + (t + 1) * 64;
        #pragma unroll
        for (int m = 0; m < 4; ++m) {
            af[m][0] = *(const short8*)&LDS[bufA + aRd + m * 1024 + c0];
            af[m][1] = *(const short8*)&LDS[bufA + aRd + m * 1024 + c1];
        }
        #pragma unroll
        for (int n = 0; n < 2; ++n) {
            bl[n][0] = *(const short8*)&LDS[bufB + bRd + n * 1024 + c0];
            bl[n][1] = *(const short8*)&LDS[bufB + bRd + n * 1024 + c1];
        }
        if (pf) { gload_lds16(ap, &LDS[sA + ldsA0]);
                  gload_lds16(bp, &LDS[sB + ldsB0]); }
        __builtin_amdgcn_s_barrier();
        __builtin_amdgcn_sched_barrier(0);
        __builtin_amdgcn_s_setprio(1);
        #pragma unroll
        for (int m = 0; m < 4; ++m)
            #pragma unroll
            for (int n = 0; n < 2; ++n) {
                acc[m][n] = __builtin_amdgcn_mfma_f32_16x16x32_bf16(af[m][0], bl[n][0], acc[m][n], 0, 0, 0);
                acc[m][n] = __builtin_amdgcn_mfma_f32_16x16x32_bf16(af[m][1], bl[n][1], acc[m][n], 0, 0, 0);
            }
        __builtin_amdgcn_s_setprio(0);
        asm volatile("s_waitcnt vmcnt(4)" ::: "memory");
        __builtin_amdgcn_s_barrier();
        __builtin_amdgcn_sched_barrier(0);
        #pragma unroll
        for (int n = 0; n < 2; ++n) {
            bh[n][0] = *(const short8*)&LDS[bufB + bRd + (n + 2) * 1024 + c0];
            bh[n][1] = *(const short8*)&LDS[bufB + bRd + (n + 2) * 1024 + c1];
        }
        if (pf) { gload_lds16(ap + (size_t)32 * K, &LDS[sA + ldsA0 + 2048]);
                  gload_lds16(bp + (size_t)16 * K, &LDS[sB + ldsB0 + 1024]); }
        __builtin_amdgcn_s_barrier();
        __builtin_amdgcn_sched_barrier(0);
        __builtin_amdgcn_s_setprio(1);
        #pragma unroll
        for (int m = 0; m < 4; ++m)
            #pragma unroll
            for (int n = 0; n < 2; ++n) {
                acc[m][n + 2] = __builtin_amdgcn_mfma_f32_16x16x32_bf16(af[m][0], bh[n][0], acc[m][n + 2], 0, 0, 0);
                acc[m][n + 2] = __builtin_amdgcn_mfma_f32_16x16x32_bf16(af[m][1], bh[n][1], acc[m][n + 2], 0, 0, 0);
            }
        __builtin_amdgcn_s_setprio(0);
        asm volatile("s_waitcnt vmcnt(4)" ::: "memory");
        __builtin_amdgcn_s_barrier();
        __builtin_amdgcn_sched_barrier(0);
        #pragma unroll
        for (int m = 0; m < 4; ++m) {
            af[m][0] = *(const short8*)&LDS[bufA + aRd + (m + 4) * 1024 + c0];
            af[m][1] = *(const short8*)&LDS[bufA + aRd + (m + 4) * 1024 + c1];
        }
        if (pf) { gload_lds16(bp + (size_t)32 * K, &LDS[sB + ldsB0 + 2048]);
                  gload_lds16(bp + (size_t)48 * K, &LDS[sB + ldsB0 + 3072]); }
        __builtin_amdgcn_s_barrier();
        __builtin_amdgcn_sched_barrier(0);
        __builtin_amdgcn_s_setprio(1);
        #pragma unroll
        for (int m = 0; m < 4; ++m)
            #pragma unroll
            for (int n = 0; n < 2; ++n) {
                acc[m + 4][n] = __builtin_amdgcn_mfma_f32_16x16x32_bf16(af[m][0], bl[n][0], acc[m + 4][n], 0, 0, 0);
                acc[m + 4][n] = __builtin_amdgcn_mfma_f32_16x16x32_bf16(af[m][1], bl[n][1], acc[m + 4][n], 0, 0, 0);
            }
        __builtin_amdgcn_s_setprio(0);
        __builtin_amdgcn_s_barrier();
        __builtin_amdgcn_sched_barrier(0);
        if (pf) { gload_lds16(ap + (size_t)64 * K, &LDS[sA + ldsA0 + 4096]);
                  gload_lds16(ap + (size_t)96 * K, &LDS[sA + ldsA0 + 6144]); }
        __builtin_amdgcn_s_barrier();
        __builtin_amdgcn_sched_barrier(0);
        __builtin_amdgcn_s_setprio(1);
        #pragma unroll
        for (int m = 0; m < 4; ++m)
            #pragma unroll
            for (int n = 0; n < 2; ++n) {
                acc[m + 4][n + 2] = __builtin_amdgcn_mfma_f32_16x16x32_bf16(af[m][0], bh[n][0], acc[m + 4][n + 2], 0, 0, 0);
                acc[m + 4][n + 2] = __builtin_amdgcn_mfma_f32_16x16x32_bf16(af[m][1], bh[n][1], acc[m + 4][n + 2], 0, 0, 0);
            }
        __builtin_amdgcn_s_setprio(0);
        asm volatile("s_waitcnt vmcnt(4)" ::: "memory");
        __builtin_amdgcn_s_barrier();
        __builtin_amdgcn_sched_barrier(0);
    }
    #pragma unroll
    for (int m = 0; m < 8; ++m)
        #pragma unroll
        for (int n = 0; n < 4; ++n)
            #pragma unroll
            for (int j = 0; j < 4; ++j) {
                int row = brow + wr * 128 + m * 16 + l4 * 4 + j;
                int col = bcol + wc * 64 + n * 16 + l15;
                C[(size_t)row * N + col] = f2bf(acc[m][n][j]);
            }
}

// ---------------- 4-phase 256x128 GEMM (out-proj, f32 out) ----------------
// Same skeleton as gemm8p; BN=128 -> 2 B-chunks, 6 loads/tile.
// Issue order: Alo0,B0 | Alo1,B1 | Ahi0 | Ahi1 ; vmcnt: P1-end 4, P2-end 4, P4-end 3.

__global__ __launch_bounds__(512, 1)
void gemm8p_n128(const unsigned short* __restrict__ A,
                 const unsigned short* __restrict__ Bt,
                 float* __restrict__ C, int M, int N, int K) {
    __shared__ __align__(16) unsigned short LDS[49152];  // 96 KiB
    const int tid = threadIdx.x, lane = tid & 63, w = tid >> 6;
    const int wr = w >> 2, wc = w & 3;
    const int l15 = lane & 15, l4 = lane >> 4;
    int nwg = gridDim.x * gridDim.y;
    int wg = blockIdx.y * gridDim.x + blockIdx.x;
    int swz = (wg & 7) * (nwg >> 3) + (wg >> 3);
    int bx = swz % gridDim.x, by = swz / gridDim.x;
    const int brow = by * 256, bcol = bx * 128;
    const int wg_a = w & 3;
    const int wg_b = wr;
    const int rA = wg_a * 8 + (lane >> 3);
    const int rB = wg_b * 8 + (lane >> 3);
    const int cgS = ((lane & 7) ^ (lane >> 3)) * 8;
    const unsigned short* aP = A + (size_t)(brow + wr * 128 + rA) * K + cgS;
    const unsigned short* bP = Bt + (size_t)(bcol + wc * 32 + rB) * K + cgS;
    const int ldsA0 = wr * 8192 + (wg_a * 64 + lane) * 8;
    const int ldsB0 = wc * 2048 + (wg_b * 64 + lane) * 8;
    const int aRd = (wr * 128 + l15) * 64;
    const int bRd = (wc * 32 + l15) * 64;
    const int c0 = ((0 + l4) ^ (l15 & 7)) * 8;
    const int c1 = ((4 + l4) ^ (l15 & 7)) * 8;
    f32x4 acc[8][2] = {};
    const int nt = K >> 6;
    // prologue: tile0 -> buf0
    gload_lds16(aP,                  &LDS[ldsA0]);                 // Alo0
    gload_lds16(bP,                  &LDS[16384 + ldsB0]);         // B0
    gload_lds16(aP + (size_t)32 * K, &LDS[ldsA0 + 2048]);          // Alo1
    gload_lds16(bP + (size_t)16 * K, &LDS[16384 + ldsB0 + 1024]);  // B1
    gload_lds16(aP + (size_t)64 * K, &LDS[ldsA0 + 4096]);          // Ahi0
    gload_lds16(aP + (size_t)96 * K, &LDS[ldsA0 + 6144]);          // Ahi1
    asm volatile("s_waitcnt vmcnt(3)" ::: "memory");
    __builtin_amdgcn_s_barrier();
    __builtin_amdgcn_sched_barrier(0);
    short8 afl[4][2], afh[4][2], bl0[2], bl1[2];
    for (int t = 0; t < nt; ++t) {
        const int bufA = (t & 1) * 24576, bufB = bufA + 16384;
        const bool pf = (t + 1) < nt;
        const int sA = ((t + 1) & 1) * 24576, sB = sA + 16384;
        const unsigned short* ap = aP + (t + 1) * 64;
        const unsigned short* bp = bP + (t + 1) * 64;
        // P1: m0-3 x n0
        #pragma unroll
        for (int m = 0; m < 4; ++m) {
            afl[m][0] = *(const short8*)&LDS[bufA + aRd + m * 1024 + c0];
            afl[m][1] = *(const short8*)&LDS[bufA + aRd + m * 1024 + c1];
        }
        bl0[0] = *(const short8*)&LDS[bufB + bRd + c0];
        bl0[1] = *(const short8*)&LDS[bufB + bRd + c1];
        if (pf) { gload_lds16(ap, &LDS[sA + ldsA0]);
                  gload_lds16(bp, &LDS[sB + ldsB0]); }
        __builtin_amdgcn_s_barrier();
        __builtin_amdgcn_sched_barrier(0);
        __builtin_amdgcn_s_setprio(1);
        #pragma unroll
        for (int m = 0; m < 4; ++m) {
            acc[m][0] = __builtin_amdgcn_mfma_f32_16x16x32_bf16(afl[m][0], bl0[0], acc[m][0], 0, 0, 0);
            acc[m][0] = __builtin_amdgcn_mfma_f32_16x16x32_bf16(afl[m][1], bl0[1], acc[m][0], 0, 0, 0);
        }
        __builtin_amdgcn_s_setprio(0);
        asm volatile("s_waitcnt vmcnt(4)" ::: "memory");
        __builtin_amdgcn_s_barrier();
        __builtin_amdgcn_sched_barrier(0);
        // P2: m0-3 x n1
        bl1[0] = *(const short8*)&LDS[bufB + bRd + 1024 + c0];
        bl1[1] = *(const short8*)&LDS[bufB + bRd + 1024 + c1];
        if (pf) { gload_lds16(ap + (size_t)32 * K, &LDS[sA + ldsA0 + 2048]);
                  gload_lds16(bp + (size_t)16 * K, &LDS[sB + ldsB0 + 1024]); }
        __builtin_amdgcn_s_barrier();
        __builtin_amdgcn_sched_barrier(0);
        __builtin_amdgcn_s_setprio(1);
        #pragma unroll
        for (int m = 0; m < 4; ++m) {
            acc[m][1] = __builtin_amdgcn_mfma_f32_16x16x32_bf16(afl[m][0], bl1[0], acc[m][1], 0, 0, 0);
            acc[m][1] = __builtin_amdgcn_mfma_f32_16x16x32_bf16(afl[m][1], bl1[1], acc[m][1], 0, 0, 0);
        }
        __builtin_amdgcn_s_setprio(0);
        asm volatile("s_waitcnt vmcnt(4)" ::: "memory");
        __builtin_amdgcn_s_barrier();
        __builtin_amdgcn_sched_barrier(0);
        // P3: m4-7 x n0
        #pragma unroll
        for (int m = 0; m < 4; ++m) {
            afh[m][0] = *(const short8*)&LDS[bufA + aRd + (m + 4) * 1024 + c0];
            afh[m][1] = *(const short8*)&LDS[bufA + aRd + (m + 4) * 1024 + c1];
        }
        if (pf) gload_lds16(ap + (size_t)64 * K, &LDS[sA + ldsA0 + 4096]);
        __builtin_amdgcn_s_barrier();
        __builtin_amdgcn_sched_barrier(0);
        __builtin_amdgcn_s_setprio(1);
        #pragma unroll
        for (int m = 0; m < 4; ++m) {
            acc[m + 4][0] = __builtin_amdgcn_mfma_f32_16x16x32_bf16(afh[m][0], bl0[0], acc[m + 4][0], 0, 0, 0);
            acc[m + 4][0] = __builtin_amdgcn_mfma_f32_16x16x32_bf16(afh[m][1], bl0[1], acc[m + 4][0], 0, 0, 0);
        }
        __builtin_amdgcn_s_setprio(0);
        __builtin_amdgcn_s_barrier();
        __builtin_amdgcn_sched_barrier(0);
        // P4: m4-7 x n1
        if (pf) gload_lds16(ap + (size_t)96 * K, &LDS[sA + ldsA0 + 6144]);
        __builtin_amdgcn_s_barrier();
        __builtin_amdgcn_sched_barrier(0);
        __builtin_amdgcn_s_setprio(1);
        #pragma unroll
        for (int m = 0; m < 4; ++m) {
            acc[m + 4][1] = __builtin_amdgcn_mfma_f32_16x16x32_bf16(afh[m][0], bl1[0], acc[m + 4][1], 0, 0, 0);
            acc[m + 4][1] = __builtin_amdgcn_mfma_f32_16x16x32_bf16(afh[m][1], bl1[1], acc[m + 4][1], 0, 0, 0);
        }
        __builtin_amdgcn_s_setprio(0);
        asm volatile("s_waitcnt vmcnt(3)" ::: "memory");
        __builtin_amdgcn_s_barrier();
        __builtin_amdgcn_sched_barrier(0);
    }
    #pragma unroll
    for (int m = 0; m < 8; ++m)
        #pragma unroll
        for (int n = 0; n < 2; ++n)
            #pragma unroll
            for (int j = 0; j < 4; ++j) {
                int row = brow + wr * 128 + m * 16 + l4 * 4 + j;
                int col = bcol + wc * 32 + n * 16 + l15;
                C[(size_t)row * N + col] = acc[m][n][j];
            }
}

// ---------------- RoPE (Q/K only) ----------------
__global__ void rope_reshape(const unsigned short* __restrict__ qkv,
                             const int* __restrict__ segpos,
                             unsigned short* __restrict__ q_r,
                             unsigned short* __restrict__ k_r) {
    const int bt = blockIdx.x;
    const int hd = blockIdx.y * 2 + (threadIdx.x >> 7);  // 0..23
    const int b = bt >> 11, t = bt & 2047;
    const int h = threadIdx.x & 127;
    const unsigned short* in = (hd < 16)
        ? qkv + (size_t)bt * 4096 + hd * 128
        : qkv + (size_t)bt * 4096 + 2048 + (hd - 16) * 128;
    int pos = segpos[bt];
    int i = h & 63;
    float inv_ts = __expf((float)i * (-9.210340371976184f / 64.f));
    float ang = (float)pos * inv_ts;
    float s = __sinf(ang), c = __cosf(ang);
    float x1 = bf2f(in[i]);
    float x2 = bf2f(in[i + 64]);
    float o = (h < 64) ? (x1 * c - x2 * s) : (x2 * c + x1 * s);
    if (hd < 16) {
        o *= 0.08838834764831845f;
        q_r[((size_t)((b * 16 + hd) * 2048 + t)) * 128 + h] = f2bf(o);
    } else {
        int kh = hd - 16;
        k_r[((size_t)((b * 8 + kh) * 2048 + t)) * 128 + h] = f2bf(o);
    }
}

// ---------------- V transpose (LDS-tiled, coalesced both sides) ----------------
__global__ void v_transpose(const unsigned short* __restrict__ qkv,
                            unsigned short* __restrict__ v_t) {
    __shared__ unsigned short tile[64][72];
    const int tt0 = blockIdx.x * 64;
    const int kh = blockIdx.y >> 1, hb = (blockIdx.y & 1) * 64;
    const int b = blockIdx.z;
    int c = threadIdx.x & 63, rq = threadIdx.x >> 6;
    #pragma unroll
    for (int r = 0; r < 16; ++r) {
        int tt = r * 4 + rq;
        tile[tt][c] = qkv[(size_t)(b * 2048 + tt0 + tt) * 4096 + 3072 + kh * 128 + hb + c];
    }
    __syncthreads();
    #pragma unroll
    for (int r = 0; r < 16; ++r) {
        int hr = r * 4 + rq;
        v_t[((size_t)(b * 8 + kh) * 128 + hb + hr) * 2048 + tt0 + c] = tile[c][hr];
    }
}

// ---------------- flash attention (windowed, soft-cap, FIXED-MAX softmax) ----------------
// Soft-cap bounds logits to (-50,50): use constant max 50 -> no online max tracking,
// no rescale, l-reduce deferred to end. Masks only on first (window) and diag (causal) tiles.

__device__ __forceinline__ void stage_kv(const unsigned short* kbase, const unsigned short* vbase,
                                         unsigned short* Ksb, unsigned short* Vtb,
                                         int st, int tid) {
    #pragma unroll
    for (int r = 0; r < 2; ++r) {
        int e = (r * 512 + tid) * 8;
        int krow = e >> 7, kcol = e & 127;
        gload_lds16(kbase + (size_t)(st * 64 + krow) * 128 + (kcol ^ ((krow & 7) << 3)), Ksb + e);
        int vrow = e >> 6, vcol = e & 63;
        gload_lds16(vbase + (size_t)vrow * 2048 + st * 64 + (vcol ^ ((vrow & 7) << 3)), Vtb + e);
    }
}

__global__ __launch_bounds__(512, 4)
void attn_kernel(const unsigned short* __restrict__ q_r,
                 const unsigned short* __restrict__ k_r,
                 const unsigned short* __restrict__ v_t,
                 unsigned short* __restrict__ enc) {
    __shared__ __align__(16) unsigned short Ks[2][64 * 128];
    __shared__ __align__(16) unsigned short Vt[2][128 * 64];
    __shared__ __align__(16) unsigned short Pl[8][16 * 64];
    const int tid = threadIdx.x, lane = tid & 63, wave = tid >> 6;
    const int l15 = lane & 15, l4 = lane >> 4;
    // XCD-aware remap: all 32 qb-blocks of one (b,kh) land on one XCD (K/V L2-resident)
    const int flat = blockIdx.x;
    const int xcd = flat & 7, g = flat >> 3;
    const int pair = xcd * 2 + (g >> 5);
    const int qb = 31 - (g & 31);          // heavy-first within XCD
    const int kh = pair >> 1, b = pair & 1;
    const int n = kh * 2 + (wave >> 2);
    const int wq = wave & 3;
    short8 qf[4];
    {
        const unsigned short* qp =
            q_r + ((size_t)((b * 16 + n) * 2048 + qb * 64 + wq * 16 + l15)) * 128 + l4 * 8;
        #pragma unroll
        for (int kk = 0; kk < 4; ++kk) qf[kk] = *(const short8*)(qp + kk * 32);
    }
    f32x4 Of[8] = {};
    float lrow[4] = {};
    int t_lo = qb * 64 - 1023; if (t_lo < 0) t_lo = 0;
    const int st0 = t_lo >> 6;
    const unsigned short* kbase = k_r + (size_t)(b * 8 + kh) * 2048 * 128;
    const unsigned short* vbase = v_t + (size_t)(b * 8 + kh) * 128 * 2048;

    stage_kv(kbase, vbase, Ks[0], Vt[0], st0, tid);
    __syncthreads();
    int cur = 0;
    for (int st = st0; st <= qb; ++st) {
        if (st < qb)
            stage_kv(kbase, vbase, Ks[cur ^ 1], Vt[cur ^ 1], st + 1, tid);
        // ---- QK^T ----
        f32x4 sf[4] = {};
        #pragma unroll
        for (int nc = 0; nc < 4; ++nc) {
            int row = nc * 16 + l15;
            int sw = (l15 & 7) << 3;
            #pragma unroll
            for (int kk = 0; kk < 4; ++kk) {
                short8 bfr = *(const short8*)&Ks[cur][row * 128 + ((kk * 32 + l4 * 8) ^ sw)];
                sf[nc] = __builtin_amdgcn_mfma_f32_16x16x32_bf16(qf[kk], bfr, sf[nc], 0, 0, 0);
            }
        }
        // ---- softcap + fixed-max softmax: p = exp(50*tanh(x/50) - 50) = exp(-100/(e^{x/25}+1))
        const int mode = (st == qb) ? 1 : ((qb >= 16 && st == st0) ? 2 : 0);
        #pragma unroll
        for (int j = 0; j < 4; ++j) {
            int trow = qb * 64 + wq * 16 + l4 * 4 + j;
            int prow = l4 * 4 + j;
            int psw = (prow & 7) << 3;
            #pragma unroll
            for (int nc = 0; nc < 4; ++nc) {
                float ex = __expf(sf[nc][j] * 0.04f);
                float p = __expf(-100.f * __builtin_amdgcn_rcpf(ex + 1.f));
                if (mode) {
                    int s = st * 64 + nc * 16 + l15;
                    bool ok = (mode == 1) ? (s <= trow) : (s >= trow - 1023);
                    p = ok ? p : 0.f;
                }
                lrow[j] += p;
                Pl[wave][prow * 64 + ((nc * 16 + l15) ^ psw)] = f2bf(p);
            }
        }
        // ---- PV ----
        {
            int asw = (l15 & 7) << 3;
            #pragma unroll
            for (int ks = 0; ks < 2; ++ks) {
                short8 af = *(const short8*)&Pl[wave][l15 * 64 + ((ks * 32 + l4 * 8) ^ asw)];
                #pragma unroll
                for (int hc = 0; hc < 8; ++hc) {
                    int vrow = hc * 16 + l15;
                    short8 bfr = *(const short8*)&Vt[cur][vrow * 64 + ((ks * 32 + l4 * 8) ^ asw)];
                    Of[hc] = __builtin_amdgcn_mfma_f32_16x16x32_bf16(af, bfr, Of[hc], 0, 0, 0);
                }
            }
        }
        __syncthreads();
        cur ^= 1;
    }
    float inv[4];
    #pragma unroll
    for (int j = 0; j < 4; ++j) {
        float l = lrow[j];
        l += __shfl_xor(l, 1); l += __shfl_xor(l, 2);
        l += __shfl_xor(l, 4); l += __shfl_xor(l, 8);
        inv[j] = 1.f / l;
    }
    #pragma unroll
    for (int hc = 0; hc < 8; ++hc)
        #pragma unroll
        for (int j = 0; j < 4; ++j) {
            size_t row = (size_t)(b * 2048 + qb * 64 + wq * 16 + l4 * 4 + j);
            enc[row * 2048 + n * 128 + hc * 16 + l15] = f2bf(Of[hc][j] * inv[j]);
        }
}

// ---------------- launch ----------------

extern "C" void kernel_launch(void* const* d_in, const int* in_sizes, int n_in,
                              void* d_out, int out_size, void* d_ws, size_t ws_size,
                              hipStream_t stream) {
    const float* x   = (const float*)d_in[0];
    const int* segp  = (const int*)d_in[1];
    const float* wq  = (const float*)d_in[3];
    const float* wkv = (const float*)d_in[4];
    const float* wo  = (const float*)d_in[5];
    float* out = (float*)d_out;
    char* ws = (char*)d_ws;
    if (ws_size < ((size_t)96 << 20)) return;

    unsigned short* xb    = (unsigned short*)(ws);
    unsigned short* wqkvt = (unsigned short*)(ws + ((size_t)16 << 20));
    unsigned short* qkv   = (unsigned short*)(ws + ((size_t)32 << 20));
    unsigned short* q_r   = (unsigned short*)(ws + ((size_t)64 << 20));
    unsigned short* k_r   = (unsigned short*)(ws + ((size_t)80 << 20));
    unsigned short* v_t   = (unsigned short*)(ws + ((size_t)88 << 20));
    unsigned short* wo_t  = (unsigned short*)(ws);
    unsigned short* enc   = (unsigned short*)(ws + ((size_t)32 << 20));

    conv_x<<<8192, 256, 0, stream>>>(x, xb);
    conv_wqkvt<<<dim3(32, 64), 256, 0, stream>>>(wq, wkv, wqkvt);
    gemm8p<<<dim3(16, 16), 512, 0, stream>>>(xb, wqkvt, qkv, 4096, 4096, 2048);
    rope_reshape<<<dim3(4096, 12), 256, 0, stream>>>(qkv, segp, q_r, k_r);
    v_transpose<<<dim3(32, 16, 2), 256, 0, stream>>>(qkv, v_t);
    conv_wot<<<dim3(32, 32), 256, 0, stream>>>(wo, wo_t);
    attn_kernel<<<512, 512, 0, stream>>>(q_r, k_r, v_t, enc);
    gemm8p_n128<<<dim3(16, 16), 512, 0, stream>>>(enc, wo_t, out, 4096, 2048, 2048);
}